// Round 3
// baseline (105.715 us; speedup 1.0000x reference)
//
#include <hip/hip_runtime.h>

// YOLOv1 head post-process. One block (512 thr = 8 waves) per batch image.
// R3: R2 was store-bound — 3x float2 stores at 24B lane stride ran the write
// phase at 1.1 TB/s. Writer now stages 512-row chunks (12 KB) in LDS and
// copies them out as fully-coalesced float4 streams.
// NMS design (from R2): class-independent IoU adjacency bitmasks, per-class
// candidate compaction + rank-count stable sort, O(K) single-lane greedy scan.
// Equivalence: boxes with score < SCORE_T only suppress boxes even later in
// sort order (all zeroed by the final score filter) -> NMS over candidates
// with score >= SCORE_T is exact. ORing the full symmetric adj row is safe:
// bits for earlier ranks are already decided when set.

namespace {
constexpr int kS    = 7;
constexpr int kC    = 20;
constexpr int kFeat = 30;             // C + 5*BBOX
constexpr int kN    = 98;             // S*S*2 boxes
constexpr int kRows = kN * kC;        // 1960
constexpr int kOutF = kRows * 6;      // 11760 floats per batch
constexpr int kT    = 512;            // threads per block (8 waves)
constexpr float kIouT   = 0.5f;
constexpr float kScoreT = 0.05f;
}

__device__ __forceinline__ float iou_f(float ax1, float ay1, float ax2, float ay2,
                                       float bx1, float by1, float bx2, float by2) {
#pragma clang fp contract(off)
    float aa = fmaxf(ax2 - ax1, 0.f) * fmaxf(ay2 - ay1, 0.f);
    float ab = fmaxf(bx2 - bx1, 0.f) * fmaxf(by2 - by1, 0.f);
    float ix1 = fmaxf(ax1, bx1);
    float iy1 = fmaxf(ay1, by1);
    float ix2 = fminf(ax2, bx2);
    float iy2 = fminf(ay2, by2);
    float inter = fmaxf(ix2 - ix1, 0.f) * fmaxf(iy2 - iy1, 0.f);
    float uni = aa + ab - inter;
    return inter / fmaxf(uni, 1e-9f);
}

__global__ __launch_bounds__(kT) void yolo_head_kernel(const float* __restrict__ x,
                                                       float* __restrict__ out) {
    __shared__ float xs[kS * kS * kFeat];          // 1470 raw input floats
    __shared__ float scT[kC * kN];                 // scores [c][n] (stride-1 in n)
    __shared__ float bxs[kN * 4];                  // boxes  [n][x1,y1,x2,y2]
    __shared__ unsigned adj[kN][4];                // IoU>T bitmask rows (128 bits)
    __shared__ float cscore[8][kN];                // per-wave compacted scores
    __shared__ unsigned short cidx[8][kN];         // per-wave compacted box idx
    __shared__ unsigned short ord[8][kN];          // per-wave rank -> box idx
    __shared__ unsigned km[kC][4];                 // keep bitmask per class
    __shared__ float stage[kT * 6];                // 12 KB output staging chunk

    const int b   = blockIdx.x;
    const int tid = threadIdx.x;
    const float* xb = x + (size_t)b * (kS * kS * kFeat);

    // input slice: 1470 floats = 735 float2 (batch stride 5880 B, 8B-aligned)
    {
        const float2* xb2 = reinterpret_cast<const float2*>(xb);
        float2* xs2 = reinterpret_cast<float2*>(xs);
        for (int e = tid; e < (kS * kS * kFeat) / 2; e += kT) xs2[e] = xb2[e];
    }
    __syncthreads();

    if (tid < kS * kS) {
#pragma clang fp contract(off)
        // softmax over 20 classes for this cell, then scores for both bboxes
        const int cell = tid;
        const float* p = &xs[cell * kFeat];
        float mx = p[0];
        for (int c = 1; c < kC; ++c) mx = fmaxf(mx, p[c]);
        float e[kC];
        float sum = 0.f;
        for (int c = 0; c < kC; ++c) { e[c] = expf(p[c] - mx); sum += e[c]; }
        float conf0 = p[28], conf1 = p[29];
        for (int c = 0; c < kC; ++c) {
            float pr = e[c] / sum;
            scT[c * kN + 2 * cell]     = pr * conf0;
            scT[c * kN + 2 * cell + 1] = pr * conf1;
        }
    } else if (tid >= 64 && tid < 64 + kN) {
#pragma clang fp contract(off)
        // box decode for box n
        const int n = tid - 64;
        const int cell = n >> 1, k = n & 1;
        const int gi = cell / kS, gj = cell % kS;   // gy=gi, gx=gj
        const float* p = &xs[cell * kFeat + kC + 4 * k];
        float cx = (p[0] + (float)gj) / 7.0f;
        float cy = (p[1] + (float)gi) / 7.0f;
        float w = p[2], h = p[3];
        bxs[n * 4 + 0] = fminf(fmaxf(cx - w * 0.5f, 0.f), 1.f) * 448.f;
        bxs[n * 4 + 1] = fminf(fmaxf(cy - h * 0.5f, 0.f), 1.f) * 448.f;
        bxs[n * 4 + 2] = fminf(fmaxf(cx + w * 0.5f, 0.f), 1.f) * 448.f;
        bxs[n * 4 + 3] = fminf(fmaxf(cy + h * 0.5f, 0.f), 1.f) * 448.f;
    }
    __syncthreads();

    // ---- per-batch IoU adjacency: thread (i = t%98, w = t/98) fills word w ----
    if (tid < 4 * kN) {
        const int i = tid % kN;       // consecutive lanes -> consecutive i
        const int w = tid / kN;       // wave-uniform word -> broadcast j-loads
        const float ax1 = bxs[i * 4 + 0], ay1 = bxs[i * 4 + 1];
        const float ax2 = bxs[i * 4 + 2], ay2 = bxs[i * 4 + 3];
        unsigned m = 0;
        const int j0 = 32 * w;
        const int j1 = (j0 + 32 < kN) ? (j0 + 32) : kN;
        for (int j = j0; j < j1; ++j) {
            float v = iou_f(ax1, ay1, ax2, ay2,
                            bxs[j * 4 + 0], bxs[j * 4 + 1],
                            bxs[j * 4 + 2], bxs[j * 4 + 3]);
            if (v > kIouT) m |= (1u << (j - j0));
        }
        adj[i][w] = m;
    }
    __syncthreads();

    // ---- per-class NMS: wave wv handles classes wv, wv+8, wv+16 ----
    const int wv = tid >> 6;
    const int lane = tid & 63;
    for (int c = wv; c < kC; c += 8) {
        // candidacy
        float s0 = scT[c * kN + lane];
        bool c0 = (s0 >= kScoreT);
        float s1 = 0.f;
        bool c1 = false;
        if (lane < kN - 64) {
            s1 = scT[c * kN + 64 + lane];
            c1 = (s1 >= kScoreT);
        }
        unsigned long long m0 = __ballot(c0);
        unsigned long long m1 = __ballot(c1);
        const int K0 = __popcll(m0);
        const int K  = K0 + __popcll(m1);
        // compact (index-ascending order preserved)
        if (c0) {
            int p = __popcll(m0 & ((1ull << lane) - 1ull));
            cidx[wv][p] = (unsigned short)lane;
            cscore[wv][p] = s0;
        }
        if (c1) {
            int p = K0 + __popcll(m1 & ((1ull << lane) - 1ull));
            cidx[wv][p] = (unsigned short)(lane + 64);
            cscore[wv][p] = s1;
        }
        __builtin_amdgcn_wave_barrier();
        // rank = # candidates strictly ahead in (score desc, index asc) order
        const bool o0 = (lane < K);
        const bool o1 = (lane + 64 < K);
        float t0 = o0 ? cscore[wv][lane] : 0.f;
        float t1 = o1 ? cscore[wv][lane + 64] : 0.f;
        int r0 = 0, r1 = 0;
        for (int q = 0; q < K; ++q) {
            float sq = cscore[wv][q];     // broadcast read
            r0 += ((sq > t0) || ((sq == t0) && (q < lane))) ? 1 : 0;
            r1 += ((sq > t1) || ((sq == t1) && (q < lane + 64))) ? 1 : 0;
        }
        if (o0) ord[wv][r0] = cidx[wv][lane];
        if (o1) ord[wv][r1] = cidx[wv][lane + 64];
        __builtin_amdgcn_wave_barrier();
        // greedy scan over ranks (single lane, O(K), no shuffles)
        if (lane == 0) {
            unsigned long long supLo = 0, supHi = 0, kpLo = 0, kpHi = 0;
            for (int r = 0; r < K; ++r) {
                const int i = ord[wv][r];
                const bool dead = (i < 64) ? ((supLo >> i) & 1ull)
                                           : ((supHi >> (i - 64)) & 1ull);
                if (!dead) {
                    if (i < 64) kpLo |= (1ull << i);
                    else        kpHi |= (1ull << (i - 64));
                    supLo |= (unsigned long long)adj[i][0]
                           | ((unsigned long long)adj[i][1] << 32);
                    supHi |= (unsigned long long)adj[i][2]
                           | ((unsigned long long)adj[i][3] << 32);
                }
            }
            km[c][0] = (unsigned)kpLo;
            km[c][1] = (unsigned)(kpLo >> 32);
            km[c][2] = (unsigned)kpHi;
            km[c][3] = (unsigned)(kpHi >> 32);
        }
    }
    __syncthreads();

    // ---- output via LDS staging: build 512 rows, then coalesced float4 copy ----
    float* ob = out + (size_t)b * kOutF;
    for (int r0 = 0; r0 < kRows; r0 += kT) {
        const int r = r0 + tid;
        if (r < kRows) {
            const int n = r / kC;                 // 20 consecutive lanes share n
            const int c = r - n * kC;
            const bool kp = (km[c][n >> 5] >> (n & 31)) & 1u;
            const float m = kp ? 1.f : 0.f;
            float* st = &stage[tid * 6];
            st[0] = m * (float)c;
            st[1] = m * bxs[n * 4 + 0];
            st[2] = m * bxs[n * 4 + 1];
            st[3] = m * bxs[n * 4 + 2];
            st[4] = m * bxs[n * 4 + 3];
            st[5] = m * scT[c * kN + n];
        }
        __syncthreads();
        const int nrows = (kRows - r0 < kT) ? (kRows - r0) : kT;
        const int nq = (nrows * 6) / 4;           // 768 / 768 / 768 / 636
        const float4* s4 = reinterpret_cast<const float4*>(stage);
        float4* o4 = reinterpret_cast<float4*>(ob + (size_t)r0 * 6);
        for (int q = tid; q < nq; q += kT) o4[q] = s4[q];
        __syncthreads();
    }
}

extern "C" void kernel_launch(void* const* d_in, const int* in_sizes, int n_in,
                              void* d_out, int out_size, void* d_ws, size_t ws_size,
                              hipStream_t stream) {
    const float* x = (const float*)d_in[0];
    float* out = (float*)d_out;
    const int B = in_sizes[0] / (kS * kS * kFeat);   // 1024
    hipLaunchKernelGGL(yolo_head_kernel, dim3(B), dim3(kT), 0, stream, x, out);
}

// Round 4
// 102.317 us; speedup vs baseline: 1.0332x; 1.0332x over previous
//
#include <hip/hip_runtime.h>

// YOLOv1 head post-process. One block (512 thr = 8 waves) per batch image.
// R4: R3 showed the writer was never the bottleneck (writer rewrite = 0 delta,
// conflicts bit-identical) — the wall is the lane-0 NMS scan's dependent LDS
// chain (~250 cyc/iter) with zero spare residency to hide it. This round:
//  (a) rank-space 64-bit adjacency rows held in registers, greedy scan via
//      __shfl (shuffles independent of the sup chain -> ~10 cyc/iter),
//  (b) all-pairs 98x98 adjacency phase deleted (rank-space IoUs, K<=64),
//  (c) barrier-free writer: threads compute output float4s directly (no
//      staging LDS, no vmcnt-draining __syncthreads between chunks).
// Equivalence: boxes with score < SCORE_T sort strictly after all candidates
// and only suppress even-later boxes (all zeroed by the final score filter) ->
// NMS over candidates with score >= SCORE_T is exact. Rank tie-break = box
// index ascending = jnp stable argsort(-scores). K>64 (prob ~0) falls back to
// a ballot-style greedy loop over candidates only.

namespace {
constexpr int kS    = 7;
constexpr int kC    = 20;
constexpr int kFeat = 30;             // C + 5*BBOX
constexpr int kN    = 98;             // S*S*2 boxes
constexpr int kRows = kN * kC;        // 1960
constexpr int kOutF = kRows * 6;      // 11760 floats per batch
constexpr int kQuads = kOutF / 4;     // 2940 float4 per batch
constexpr int kT    = 512;            // threads per block (8 waves)
constexpr float kIouT   = 0.5f;
constexpr float kScoreT = 0.05f;
}

__device__ __forceinline__ float iou_f(float ax1, float ay1, float ax2, float ay2,
                                       float bx1, float by1, float bx2, float by2) {
#pragma clang fp contract(off)
    float aa = fmaxf(ax2 - ax1, 0.f) * fmaxf(ay2 - ay1, 0.f);
    float ab = fmaxf(bx2 - bx1, 0.f) * fmaxf(by2 - by1, 0.f);
    float ix1 = fmaxf(ax1, bx1);
    float iy1 = fmaxf(ay1, by1);
    float ix2 = fminf(ax2, bx2);
    float iy2 = fminf(ay2, by2);
    float inter = fmaxf(ix2 - ix1, 0.f) * fmaxf(iy2 - iy1, 0.f);
    float uni = aa + ab - inter;
    return inter / fmaxf(uni, 1e-9f);
}

__global__ __launch_bounds__(kT) void yolo_head_kernel(const float* __restrict__ x,
                                                       float* __restrict__ out) {
    __shared__ __align__(16) float xs[kS * kS * kFeat];     // 1470 input floats
    __shared__ __align__(16) float scT[kC * kN];            // scores [c][n]
    __shared__ __align__(16) float bxs[kN * 4];             // boxes [n][4]
    __shared__ __align__(16) float cscore[8][kN];           // per-wave cand scores
    __shared__ unsigned short cidx[8][kN];                  // per-wave cand box idx
    __shared__ unsigned short rnk[8][64];                   // per-wave cand -> rank
    __shared__ __align__(16) float rankbox[8][64][4];       // per-wave rank -> box
    __shared__ unsigned km[kC][4];                          // keep bitmask per class

    const int b   = blockIdx.x;
    const int tid = threadIdx.x;
    const float* xb = x + (size_t)b * (kS * kS * kFeat);

    // input slice: 1470 floats = 735 float2 (batch stride 5880 B, 8B-aligned)
    {
        const float2* xb2 = reinterpret_cast<const float2*>(xb);
        float2* xs2 = reinterpret_cast<float2*>(xs);
        for (int e = tid; e < (kS * kS * kFeat) / 2; e += kT) xs2[e] = xb2[e];
    }
    __syncthreads();

    if (tid < kS * kS) {
#pragma clang fp contract(off)
        // softmax over 20 classes for this cell, then scores for both bboxes
        const int cell = tid;
        const float* p = &xs[cell * kFeat];
        float mx = p[0];
        for (int c = 1; c < kC; ++c) mx = fmaxf(mx, p[c]);
        float e[kC];
        float sum = 0.f;
        for (int c = 0; c < kC; ++c) { e[c] = expf(p[c] - mx); sum += e[c]; }
        float conf0 = p[28], conf1 = p[29];
        for (int c = 0; c < kC; ++c) {
            float pr = e[c] / sum;
            scT[c * kN + 2 * cell]     = pr * conf0;
            scT[c * kN + 2 * cell + 1] = pr * conf1;
        }
    } else if (tid >= 64 && tid < 64 + kN) {
#pragma clang fp contract(off)
        // box decode for box n
        const int n = tid - 64;
        const int cell = n >> 1, k = n & 1;
        const int gi = cell / kS, gj = cell % kS;   // gy=gi, gx=gj
        const float* p = &xs[cell * kFeat + kC + 4 * k];
        float cx = (p[0] + (float)gj) / 7.0f;
        float cy = (p[1] + (float)gi) / 7.0f;
        float w = p[2], h = p[3];
        bxs[n * 4 + 0] = fminf(fmaxf(cx - w * 0.5f, 0.f), 1.f) * 448.f;
        bxs[n * 4 + 1] = fminf(fmaxf(cy - h * 0.5f, 0.f), 1.f) * 448.f;
        bxs[n * 4 + 2] = fminf(fmaxf(cx + w * 0.5f, 0.f), 1.f) * 448.f;
        bxs[n * 4 + 3] = fminf(fmaxf(cy + h * 0.5f, 0.f), 1.f) * 448.f;
    }
    __syncthreads();

    // ---- per-class NMS: wave wv handles classes wv, wv+8, wv+16 ----
    const int wv = tid >> 6;
    const int lane = tid & 63;
    for (int c = wv; c < kC; c += 8) {
        // candidacy over both halves (boxes lane and lane+64)
        float s0 = scT[c * kN + lane];
        bool c0 = (s0 >= kScoreT);
        float s1 = 0.f;
        bool c1 = false;
        if (lane < kN - 64) {
            s1 = scT[c * kN + 64 + lane];
            c1 = (s1 >= kScoreT);
        }
        unsigned long long m0 = __ballot(c0);
        unsigned long long m1 = __ballot(c1);
        const int K0 = __popcll(m0);
        const int K  = K0 + __popcll(m1);
        int p0 = 0, p1 = 0;
        if (c0) {
            p0 = __popcll(m0 & ((1ull << lane) - 1ull));
            cscore[wv][p0] = s0;
            cidx[wv][p0] = (unsigned short)lane;
        }
        if (c1) {
            p1 = K0 + __popcll(m1 & ((1ull << lane) - 1ull));
            cscore[wv][p1] = s1;
            cidx[wv][p1] = (unsigned short)(lane + 64);
        }
        __builtin_amdgcn_wave_barrier();

        unsigned long long kb0 = 0, kb1 = 0;   // keep ballots (box space)
        if (K <= 64) {
            // --- fast path: candidate p lives on lane p ---
            const bool act = (lane < K);
            float sp = act ? cscore[wv][lane] : 0.f;
            int rp = 0;
            for (int q = 0; q < K; ++q) {
                float sq = cscore[wv][q];                // broadcast read
                rp += ((sq > sp) || ((sq == sp) && (q < lane))) ? 1 : 0;
            }
            if (act) {
                rnk[wv][lane] = (unsigned short)rp;
                const int bi = cidx[wv][lane];
                const float4 bb = *reinterpret_cast<const float4*>(&bxs[bi * 4]);
                *reinterpret_cast<float4*>(&rankbox[wv][rp][0]) = bb;
            }
            __builtin_amdgcn_wave_barrier();
            // lane q takes the role of rank q: build 64-bit rank-adjacency row
            float qx1 = 0.f, qy1 = 0.f, qx2 = 0.f, qy2 = 0.f;
            if (act) {
                const float4 qb = *reinterpret_cast<const float4*>(&rankbox[wv][lane][0]);
                qx1 = qb.x; qy1 = qb.y; qx2 = qb.z; qy2 = qb.w;
            }
            unsigned long long mask = 0;
            for (int r = 0; r < K; ++r) {
                const float4 rb = *reinterpret_cast<const float4*>(&rankbox[wv][r][0]);
                float v = iou_f(qx1, qy1, qx2, qy2, rb.x, rb.y, rb.z, rb.w);
                if (v > kIouT) mask |= (1ull << r);
            }
            // greedy scan: shuffles are independent of sup -> short dep chain
            unsigned long long sup = 0, keepM = 0;
            for (int r = 0; r < K; ++r) {
                unsigned long long row = __shfl(mask, r);
                unsigned long long take = ((sup >> r) & 1ull) - 1ull; // ~0 if free
                keepM |= (1ull << r) & take;
                sup   |= row & take;
            }
            __builtin_amdgcn_wave_barrier();
            // map rank-space keep back to this lane's boxes
            const unsigned short rv0 = rnk[wv][c0 ? p0 : 0];
            const unsigned short rv1 = rnk[wv][c1 ? p1 : 0];
            const bool k0 = c0 && ((keepM >> rv0) & 1ull);
            const bool k1 = c1 && ((keepM >> rv1) & 1ull);
            kb0 = __ballot(k0);
            kb1 = __ballot(k1);
        } else {
            // --- fallback (K>64, probability ~0): ballot-greedy over candidates ---
            bool al0 = c0, al1 = c1;
            bool k0 = false, k1 = false;
            const float n0x1 = bxs[lane * 4 + 0], n0y1 = bxs[lane * 4 + 1];
            const float n0x2 = bxs[lane * 4 + 2], n0y2 = bxs[lane * 4 + 3];
            float n1x1 = 0.f, n1y1 = 0.f, n1x2 = 0.f, n1y2 = 0.f;
            if (lane < kN - 64) {
                n1x1 = bxs[(lane + 64) * 4 + 0]; n1y1 = bxs[(lane + 64) * 4 + 1];
                n1x2 = bxs[(lane + 64) * 4 + 2]; n1y2 = bxs[(lane + 64) * 4 + 3];
            }
            for (;;) {
                float bs; int bp;
                if (al0 && (!al1 || s0 >= s1)) { bs = s0; bp = p0; }
                else if (al1)                  { bs = s1; bp = p1; }
                else                           { bs = -1e30f; bp = 1 << 20; }
                for (int off = 32; off; off >>= 1) {
                    float os = __shfl_xor(bs, off);
                    int   op = __shfl_xor(bp, off);
                    if (os > bs || (os == bs && op < bp)) { bs = os; bp = op; }
                }
                if (bp >= (1 << 20)) break;
                const int bi = cidx[wv][bp];             // wave-uniform
                const float4 kbx = *reinterpret_cast<const float4*>(&bxs[bi * 4]);
                if (bp == p0 && al0) { k0 = true; al0 = false; }
                if (bp == p1 && al1) { k1 = true; al1 = false; }
                if (al0 && iou_f(kbx.x, kbx.y, kbx.z, kbx.w,
                                 n0x1, n0y1, n0x2, n0y2) > kIouT) al0 = false;
                if (al1 && iou_f(kbx.x, kbx.y, kbx.z, kbx.w,
                                 n1x1, n1y1, n1x2, n1y2) > kIouT) al1 = false;
            }
            kb0 = __ballot(k0);
            kb1 = __ballot(k1);
        }
        if (lane == 0) {
            km[c][0] = (unsigned)kb0;
            km[c][1] = (unsigned)(kb0 >> 32);
            km[c][2] = (unsigned)kb1;
            km[c][3] = (unsigned)(kb1 >> 32);
        }
    }
    __syncthreads();

    // ---- barrier-free writer: each thread emits coalesced float4 quads ----
    float* ob = out + (size_t)b * kOutF;
    for (int q = tid; q < kQuads; q += kT) {
        float4 v;
        float* vp = &v.x;
#pragma unroll
        for (int j = 0; j < 4; ++j) {
            const int f = 4 * q + j;
            const int r = f / 6;
            const int fld = f - 6 * r;
            const int n = r / kC;
            const int c = r - kC * n;
            const unsigned kp = (km[c][n >> 5] >> (n & 31)) & 1u;
            int bj = fld - 1;
            bj = bj < 0 ? 0 : (bj > 3 ? 3 : bj);
            const float bv = bxs[n * 4 + bj];
            const float sv = scT[c * kN + n];
            const float val = (fld == 0) ? (float)c : ((fld == 5) ? sv : bv);
            vp[j] = kp ? val : 0.f;
        }
        *reinterpret_cast<float4*>(ob + 4 * q) = v;
    }
}

extern "C" void kernel_launch(void* const* d_in, const int* in_sizes, int n_in,
                              void* d_out, int out_size, void* d_ws, size_t ws_size,
                              hipStream_t stream) {
    const float* x = (const float*)d_in[0];
    float* out = (float*)d_out;
    const int B = in_sizes[0] / (kS * kS * kFeat);   // 1024
    hipLaunchKernelGGL(yolo_head_kernel, dim3(B), dim3(kT), 0, stream, x, out);
}